// Round 1
// baseline (698.521 us; speedup 1.0000x reference)
//
#include <hip/hip_runtime.h>
#include <hip/hip_bf16.h>
#include <math.h>

// ---------------- problem constants ----------------
#define NB    32          // graphs
#define NPG   512         // nodes per graph
#define NTOT  (NB*NPG)    // 16384
#define EPG   4096
#define ETOT  (NB*EPG)    // 131072
#define HID   128
#define INF_  512
#define K1    308
#define K2    185
#define N2    (NB*K1)     // 9856
#define N3    (NB*K2)     // 5920
#define SLOPE 0.2f

// ---------------- fp32 GEMM: C[M,Nn] = A[M,K] @ W[K,Nn] + bias ----------------
#define BM 128
#define BN 128
#define BK 8
__global__ __launch_bounds__(256) void sgemm_bias(
    const float* __restrict__ A, const float* __restrict__ W,
    const float* __restrict__ bias, float* __restrict__ C,
    int M, int Nn, int K)
{
    __shared__ float As[BK][BM];
    __shared__ float Bs[BK][BN];
    int bx = blockIdx.x;          // N tile
    int by = blockIdx.y;          // M tile
    int tid = threadIdx.x;
    int row0 = by * BM, col0 = bx * BN;
    int am = tid >> 1;            // 0..127
    int ak = (tid & 1) * 4;       // 0 or 4
    int bk = tid >> 5;            // 0..7
    int bn = (tid & 31) * 4;      // 0..124
    int tx = tid & 15, ty = tid >> 4;
    float acc[8][8] = {};
    for (int k0 = 0; k0 < K; k0 += BK) {
        float4 av = *(const float4*)&A[(size_t)(row0 + am) * K + k0 + ak];
        float4 bv = *(const float4*)&W[(size_t)(k0 + bk) * Nn + col0 + bn];
        As[ak + 0][am] = av.x; As[ak + 1][am] = av.y;
        As[ak + 2][am] = av.z; As[ak + 3][am] = av.w;
        *(float4*)&Bs[bk][bn] = bv;
        __syncthreads();
#pragma unroll
        for (int kk = 0; kk < BK; ++kk) {
            float a[8], b[8];
            *(float4*)(a)     = *(const float4*)&As[kk][ty * 8];
            *(float4*)(a + 4) = *(const float4*)&As[kk][ty * 8 + 4];
            *(float4*)(b)     = *(const float4*)&Bs[kk][tx * 8];
            *(float4*)(b + 4) = *(const float4*)&Bs[kk][tx * 8 + 4];
#pragma unroll
            for (int i = 0; i < 8; ++i)
#pragma unroll
                for (int j = 0; j < 8; ++j)
                    acc[i][j] += a[i] * b[j];
        }
        __syncthreads();
    }
#pragma unroll
    for (int i = 0; i < 8; ++i) {
        int r = row0 + ty * 8 + i;
#pragma unroll
        for (int j = 0; j < 8; j += 4) {
            int c = col0 + tx * 8 + j;
            float4 o;
            o.x = acc[i][j + 0] + bias[c + 0];
            o.y = acc[i][j + 1] + bias[c + 1];
            o.z = acc[i][j + 2] + bias[c + 2];
            o.w = acc[i][j + 3] + bias[c + 3];
            *(float4*)&C[(size_t)r * Nn + c] = o;
        }
    }
}

// ---------------- CSR build ----------------
__global__ void count_edges(const int* __restrict__ dst, int E_in, int* __restrict__ cnt)
{
    int e = blockIdx.x * blockDim.x + threadIdx.x;
    if (e < E_in) atomicAdd(&cnt[dst[e]], 1);
}

__global__ void fill_edges(const int* __restrict__ src, const int* __restrict__ dst,
                           int E_in, int* __restrict__ next, int* __restrict__ csr)
{
    int e = blockIdx.x * blockDim.x + threadIdx.x;
    if (e < E_in) {
        int p = atomicAdd(&next[dst[e]], 1);
        csr[p] = src[e];
    }
}

// exclusive scan of cnt[0..n) -> off[0..n], also copies into next[]
__global__ __launch_bounds__(1024) void scan_excl(const int* __restrict__ cnt, int n,
                                                  int* __restrict__ off, int* __restrict__ next)
{
    __shared__ int bsum[1024];
    int t = threadIdx.x;
    int chunk = (n + 1023) >> 10;
    int lo = t * chunk, hi = min(n, lo + chunk);
    int s = 0;
    for (int i = lo; i < hi; ++i) s += cnt[i];
    bsum[t] = s;
    __syncthreads();
    for (int d = 1; d < 1024; d <<= 1) {
        int v = (t >= d) ? bsum[t - d] : 0;
        __syncthreads();
        bsum[t] += v;
        __syncthreads();
    }
    int run = t ? bsum[t - 1] : 0;
    for (int i = lo; i < hi; ++i) { off[i] = run; next[i] = run; run += cnt[i]; }
    if (t == 1023) off[n] = bsum[1023];
}

// remap edges after pooling; compacts surviving edges + counts per new-dst
__global__ void remap_edges(const int* __restrict__ src, const int* __restrict__ dst,
                            int E_in, const int* __restrict__ nmap,
                            int* __restrict__ es2, int* __restrict__ ed2,
                            int* __restrict__ ec2, int* __restrict__ cnt2)
{
    int e = blockIdx.x * blockDim.x + threadIdx.x;
    if (e >= E_in) return;
    int ns = nmap[src[e]], nd = nmap[dst[e]];
    if (ns >= 0 && nd >= 0) {
        int pos = atomicAdd(ec2, 1);
        es2[pos] = ns; ed2[pos] = nd;
        atomicAdd(&cnt2[nd], 1);
    }
}

__global__ void fill_edges_dyn(const int* __restrict__ es, const int* __restrict__ ed,
                               const int* __restrict__ ec, int* __restrict__ next,
                               int* __restrict__ csr)
{
    int e = blockIdx.x * blockDim.x + threadIdx.x;
    if (e < *ec) {
        int p = atomicAdd(&next[ed[e]], 1);
        csr[p] = es[e];
    }
}

// ---------------- GATv2 aggregation: one wave per dst node ----------------
// XL/XR: [n,512] (=[n,H=4,C=128]); out: relu(mean_h(softmax-agg) + bias)  [n,128]
__global__ __launch_bounds__(256) void gatv2_agg(
    const float* __restrict__ XL, const float* __restrict__ XR,
    const int* __restrict__ csr_src, const int* __restrict__ off,
    const float* __restrict__ att, const float* __restrict__ bias,
    float* __restrict__ out, int n)
{
    int wid = (blockIdx.x * blockDim.x + threadIdx.x) >> 6;
    int lane = threadIdx.x & 63;
    if (wid >= n) return;
    const int f0 = lane * 8;  // flat (h,c) channel base; head = lane>>4
    float xr[8], atv[8], acc[8];
#pragma unroll
    for (int j = 0; j < 8; ++j) {
        xr[j]  = XR[(size_t)wid * 512 + f0 + j];
        atv[j] = att[f0 + j];
        acc[j] = 0.f;
    }
    float m = -INFINITY, ssum = 0.f;
    int e0 = off[wid], e1 = off[wid + 1];
    for (int e = e0 - 1; e < e1; ++e) {       // e==e0-1: self loop
        int s = (e < e0) ? wid : csr_src[e];
        float xl[8], part = 0.f;
#pragma unroll
        for (int j = 0; j < 8; ++j) {
            xl[j] = XL[(size_t)s * 512 + f0 + j];
            float v = xl[j] + xr[j];
            v = (v > 0.f) ? v : SLOPE * v;
            part += v * atv[j];
        }
        // reduce logit across the 16-lane head group
        part += __shfl_xor(part, 1);
        part += __shfl_xor(part, 2);
        part += __shfl_xor(part, 4);
        part += __shfl_xor(part, 8);
        float mn = fmaxf(m, part);
        float scale = __expf(m - mn);     // exp(-inf)=0 on first iter
        float p = __expf(part - mn);
        ssum = ssum * scale + p;
#pragma unroll
        for (int j = 0; j < 8; ++j) acc[j] = acc[j] * scale + p * xl[j];
        m = mn;
    }
    float inv = 1.f / ssum;               // ssum>=~1 (self loop always present)
#pragma unroll
    for (int j = 0; j < 8; ++j) {
        float v = acc[j] * inv;
        v += __shfl_xor(v, 16);           // sum over 4 heads
        v += __shfl_xor(v, 32);
        if (lane < 16) {
            int c = lane * 8 + j;
            float r = 0.25f * v + bias[c];
            out[(size_t)wid * 128 + c] = fmaxf(r, 0.f);
        }
    }
}

// ---------------- SAGE pooling score: one wave per node ----------------
__global__ __launch_bounds__(256) void sage_score(
    const float* __restrict__ X, const int* __restrict__ csr_src,
    const int* __restrict__ off, const float* __restrict__ Wn,
    const float* __restrict__ Wr, const float* __restrict__ bs,
    float* __restrict__ score, int n)
{
    int wid = (blockIdx.x * blockDim.x + threadIdx.x) >> 6;
    int lane = threadIdx.x & 63;
    if (wid >= n) return;
    int c0 = lane * 2;
    int e0 = off[wid], e1 = off[wid + 1];
    float a0 = 0.f, a1 = 0.f;
    for (int e = e0; e < e1; ++e) {
        int s = csr_src[e];
        a0 += X[(size_t)s * 128 + c0];
        a1 += X[(size_t)s * 128 + c0 + 1];
    }
    float inv = 1.f / fmaxf((float)(e1 - e0), 1.f);
    float x0 = X[(size_t)wid * 128 + c0];
    float x1 = X[(size_t)wid * 128 + c0 + 1];
    float part = a0 * inv * Wn[c0] + a1 * inv * Wn[c0 + 1] + x0 * Wr[c0] + x1 * Wr[c0 + 1];
#pragma unroll
    for (int sh = 1; sh < 64; sh <<= 1) part += __shfl_xor(part, sh);
    if (lane == 0) score[wid] = part + bs[0];
}

// ---------------- SAGPooling top-k: exact jax.lax.top_k rank ----------------
__global__ __launch_bounds__(512) void pool_rank(const float* __restrict__ score,
                                                 int npg, int k, int* __restrict__ nmap)
{
    __shared__ float s[512];
    int b = blockIdx.x, t = threadIdx.x;
    const float* sc = score + (size_t)b * npg;
    if (t < npg) s[t] = sc[t];
    __syncthreads();
    if (t < npg) {
        float mine = s[t];
        int rank = 0;
        for (int j = 0; j < npg; ++j) {
            float v = s[j];
            rank += (v > mine) || (v == mine && j < t);
        }
        nmap[(size_t)b * npg + t] = (rank < k) ? (b * k + rank) : -1;
    }
}

__global__ void pool_gather(const float* __restrict__ X, const float* __restrict__ score,
                            const int* __restrict__ nmap, float* __restrict__ Xn)
{
    int i = blockIdx.x, c = threadIdx.x;  // 128 threads
    int nid = nmap[i];
    if (nid < 0) return;
    float t = tanhf(score[i]);
    Xn[(size_t)nid * 128 + c] = X[(size_t)i * 128 + c] * t;
}

// ---------------- global max pool ----------------
__global__ void gmp(const float* __restrict__ X, int npg, float* __restrict__ out)
{
    int b = blockIdx.x, c = threadIdx.x;  // 128 threads
    const float* p = X + (size_t)b * npg * 128 + c;
    float m = -INFINITY;
    for (int i = 0; i < npg; ++i) m = fmaxf(m, p[(size_t)i * 128]);
    out[b * 128 + c] = m;
}

// ---------------- final: relu((x1+x2+x3) @ Wf + bf) ----------------
__global__ void final_mlp(const float* __restrict__ x1, const float* __restrict__ x2,
                          const float* __restrict__ x3, const float* __restrict__ Wf,
                          const float* __restrict__ bf, float* __restrict__ out)
{
    int b = blockIdx.x, o = threadIdx.x;  // 64 threads
    float acc = bf[o];
    for (int c = 0; c < 128; ++c) {
        float xv = x1[b * 128 + c] + x2[b * 128 + c] + x3[b * 128 + c];
        acc += xv * Wf[c * 64 + o];
    }
    out[b * 64 + o] = fmaxf(acc, 0.f);
}

// ---------------- host orchestration ----------------
static inline size_t alignup(size_t x) { return (x + 255) & ~(size_t)255; }

extern "C" void kernel_launch(void* const* d_in, const int* in_sizes, int n_in,
                              void* d_out, int out_size, void* d_ws, size_t ws_size,
                              hipStream_t stream)
{
    const float* x_feat = (const float*)d_in[0];
    const int*   ei     = (const int*)d_in[1];   // [2,E]: src then dst
    const float* Wl1  = (const float*)d_in[3];
    const float* bl1  = (const float*)d_in[4];
    const float* Wr1  = (const float*)d_in[5];
    const float* br1  = (const float*)d_in[6];
    const float* att1 = (const float*)d_in[7];
    const float* bias1= (const float*)d_in[8];
    const float* Wl2  = (const float*)d_in[9];
    const float* bl2  = (const float*)d_in[10];
    const float* Wr2  = (const float*)d_in[11];
    const float* br2  = (const float*)d_in[12];
    const float* att2 = (const float*)d_in[13];
    const float* bias2= (const float*)d_in[14];
    const float* Wsn  = (const float*)d_in[15];
    const float* Wsr  = (const float*)d_in[16];
    const float* bs   = (const float*)d_in[17];
    const float* Wf   = (const float*)d_in[18];
    const float* bf   = (const float*)d_in[19];
    float* out = (float*)d_out;

    const int* e_src = ei;
    const int* e_dst = ei + ETOT;

    // ---- workspace carve-up ----
    char* ws = (char*)d_ws;
    size_t o = 0;
    auto take = [&](size_t bytes) { size_t r = o; o = alignup(o + bytes); return r; };
    float* XL   = (float*)(ws + take((size_t)NTOT * 512 * 4));
    float* XR   = (float*)(ws + take((size_t)NTOT * 512 * 4));
    float* H1   = (float*)(ws + take((size_t)NTOT * 128 * 4));   // layer-1 out (relu)
    float* PX   = (float*)(ws + take((size_t)N2 * 128 * 4));     // pooled-1 features
    float* H2   = (float*)(ws + take((size_t)N2 * 128 * 4));     // layer-2 out (relu)
    float* P2X  = (float*)(ws + take((size_t)N3 * 128 * 4));     // pooled-2 features
    float* score= (float*)(ws + take((size_t)NTOT * 4));
    int*   nmap = (int*)(ws + take((size_t)NTOT * 4));
    int*   cnt  = (int*)(ws + take((size_t)(NTOT + 1) * 4));
    int*   offs = (int*)(ws + take((size_t)(NTOT + 1) * 4));
    int*   nxt  = (int*)(ws + take((size_t)(NTOT + 1) * 4));
    int*   csr1 = (int*)(ws + take((size_t)ETOT * 4));
    int*   es2  = (int*)(ws + take((size_t)ETOT * 4));
    int*   ed2  = (int*)(ws + take((size_t)ETOT * 4));
    int*   csr2 = (int*)(ws + take((size_t)ETOT * 4));
    int*   ec2  = (int*)(ws + take(256));
    float* x1g  = (float*)(ws + take((size_t)NB * 128 * 4));
    float* x2g  = (float*)(ws + take((size_t)NB * 128 * 4));
    float* x3g  = (float*)(ws + take((size_t)NB * 128 * 4));
    (void)ws_size; (void)in_sizes; (void)n_in; (void)out_size;

    // ---- layer 1 transforms: XL = x@Wl1+bl1, XR = x@Wr1+br1 ----
    sgemm_bias<<<dim3(512 / BN, NTOT / BM), 256, 0, stream>>>(x_feat, Wl1, bl1, XL, NTOT, 512, 512);
    sgemm_bias<<<dim3(512 / BN, NTOT / BM), 256, 0, stream>>>(x_feat, Wr1, br1, XR, NTOT, 512, 512);

    // ---- CSR (by dst) of the input graph ----
    hipMemsetAsync(cnt, 0, (size_t)(NTOT + 1) * 4, stream);
    count_edges<<<ETOT / 256, 256, 0, stream>>>(e_dst, ETOT, cnt);
    scan_excl<<<1, 1024, 0, stream>>>(cnt, NTOT, offs, nxt);
    fill_edges<<<ETOT / 256, 256, 0, stream>>>(e_src, e_dst, ETOT, nxt, csr1);

    // ---- GATv2 layer 1 + relu -> H1 ----
    gatv2_agg<<<NTOT / 4, 256, 0, stream>>>(XL, XR, csr1, offs, att1, bias1, H1, NTOT);

    // ---- x1 = gmp(H1) ----
    gmp<<<NB, 128, 0, stream>>>(H1, NPG, x1g);

    // ---- SAGE score 1 + pool 1 ----
    sage_score<<<NTOT / 4, 256, 0, stream>>>(H1, csr1, offs, Wsn, Wsr, bs, score, NTOT);
    pool_rank<<<NB, 512, 0, stream>>>(score, NPG, K1, nmap);
    pool_gather<<<NTOT, 128, 0, stream>>>(H1, score, nmap, PX);

    // ---- x2 = gmp(PX) ----
    gmp<<<NB, 128, 0, stream>>>(PX, K1, x2g);

    // ---- remap + compact edges, CSR2 ----
    hipMemsetAsync(cnt, 0, (size_t)(NTOT + 1) * 4, stream);
    hipMemsetAsync(ec2, 0, 4, stream);
    remap_edges<<<ETOT / 256, 256, 0, stream>>>(e_src, e_dst, ETOT, nmap, es2, ed2, ec2, cnt);
    scan_excl<<<1, 1024, 0, stream>>>(cnt, N2, offs, nxt);
    fill_edges_dyn<<<ETOT / 256, 256, 0, stream>>>(es2, ed2, ec2, nxt, csr2);

    // ---- layer 2 transforms (K=128) ----
    sgemm_bias<<<dim3(512 / BN, N2 / BM), 256, 0, stream>>>(PX, Wl2, bl2, XL, N2, 512, 128);
    sgemm_bias<<<dim3(512 / BN, N2 / BM), 256, 0, stream>>>(PX, Wr2, br2, XR, N2, 512, 128);

    // ---- GATv2 layer 2 + relu -> H2 ----
    gatv2_agg<<<(N2 + 3) / 4, 256, 0, stream>>>(XL, XR, csr2, offs, att2, bias2, H2, N2);

    // ---- SAGE score 2 + pool 2 ----
    sage_score<<<(N2 + 3) / 4, 256, 0, stream>>>(H2, csr2, offs, Wsn, Wsr, bs, score, N2);
    pool_rank<<<NB, 512, 0, stream>>>(score, K1, K2, nmap);
    pool_gather<<<N2, 128, 0, stream>>>(H2, score, nmap, P2X);

    // ---- x3 = gmp(P2X) ----
    gmp<<<NB, 128, 0, stream>>>(P2X, K2, x3g);

    // ---- final MLP ----
    final_mlp<<<NB, 64, 0, stream>>>(x1g, x2g, x3g, Wf, bf, out);
}

// Round 2
// 649.250 us; speedup vs baseline: 1.0759x; 1.0759x over previous
//
#include <hip/hip_runtime.h>
#include <hip/hip_bf16.h>
#include <math.h>

// ---------------- problem constants ----------------
#define NB    32          // graphs
#define NPG   512         // nodes per graph
#define NTOT  (NB*NPG)    // 16384
#define EPG   4096
#define ETOT  (NB*EPG)    // 131072
#define K1    308
#define K2    185
#define N2    (NB*K1)     // 9856
#define N3    (NB*K2)     // 5920
#define SLOPE 0.2f

// ---------------- fp32 GEMM: C[M,Nn] = A[M,K] @ W[K,Nn] + bias ----------------
// 128x128 tile, 256 threads, 8x8 microtile (cols split 4+4 to avoid bank conflicts)
#define BM 128
#define BN 128
#define BK 16
#define BSP (BN + 8)      // padded Bs stride (breaks staging-write conflicts)
__global__ __launch_bounds__(256) void sgemm_bias(
    const float* __restrict__ A, const float* __restrict__ W,
    const float* __restrict__ bias, float* __restrict__ C,
    int M, int Nn, int K)
{
    __shared__ float As[BK][BM];
    __shared__ float Bs[BK][BSP];
    int tid = threadIdx.x;
    int row0 = blockIdx.y * BM, col0 = blockIdx.x * BN;
    int am = tid >> 1, ak = (tid & 1) * 8;        // A staging: 8 floats/thread
    int bk = tid >> 4, bn = (tid & 15) * 8;       // B staging: 8 floats/thread
    int tx = tid & 15, ty = tid >> 4;             // 16x16 thread grid
    float acc[8][8] = {};
    for (int k0 = 0; k0 < K; k0 += BK) {
        float4 a0 = *(const float4*)&A[(size_t)(row0 + am) * K + k0 + ak];
        float4 a1 = *(const float4*)&A[(size_t)(row0 + am) * K + k0 + ak + 4];
        float4 b0 = *(const float4*)&W[(size_t)(k0 + bk) * Nn + col0 + bn];
        float4 b1 = *(const float4*)&W[(size_t)(k0 + bk) * Nn + col0 + bn + 4];
        As[ak + 0][am] = a0.x; As[ak + 1][am] = a0.y;
        As[ak + 2][am] = a0.z; As[ak + 3][am] = a0.w;
        As[ak + 4][am] = a1.x; As[ak + 5][am] = a1.y;
        As[ak + 6][am] = a1.z; As[ak + 7][am] = a1.w;
        *(float4*)&Bs[bk][bn]     = b0;
        *(float4*)&Bs[bk][bn + 4] = b1;
        __syncthreads();
#pragma unroll
        for (int kk = 0; kk < BK; ++kk) {
            float a[8], b[8];
            *(float4*)(a)     = *(const float4*)&As[kk][ty * 8];
            *(float4*)(a + 4) = *(const float4*)&As[kk][ty * 8 + 4];
            *(float4*)(b)     = *(const float4*)&Bs[kk][tx * 4];        // cols tx*4..+3
            *(float4*)(b + 4) = *(const float4*)&Bs[kk][64 + tx * 4];   // cols 64+tx*4..+3
#pragma unroll
            for (int i = 0; i < 8; ++i)
#pragma unroll
                for (int j = 0; j < 8; ++j)
                    acc[i][j] += a[i] * b[j];
        }
        __syncthreads();
    }
#pragma unroll
    for (int i = 0; i < 8; ++i) {
        int r = row0 + ty * 8 + i;
        int c0 = col0 + tx * 4;
        int c1 = col0 + 64 + tx * 4;
        float4 o0, o1;
        o0.x = acc[i][0] + bias[c0 + 0]; o0.y = acc[i][1] + bias[c0 + 1];
        o0.z = acc[i][2] + bias[c0 + 2]; o0.w = acc[i][3] + bias[c0 + 3];
        o1.x = acc[i][4] + bias[c1 + 0]; o1.y = acc[i][5] + bias[c1 + 1];
        o1.z = acc[i][6] + bias[c1 + 2]; o1.w = acc[i][7] + bias[c1 + 3];
        *(float4*)&C[(size_t)r * Nn + c0] = o0;
        *(float4*)&C[(size_t)r * Nn + c1] = o1;
    }
}

// concat [K,512]|[K,512] -> [K,1024] (weights) and 512|512 -> 1024 (bias)
__global__ void concat_wb(const float* __restrict__ Wl, const float* __restrict__ Wr,
                          const float* __restrict__ bl, const float* __restrict__ br,
                          float* __restrict__ Wc, float* __restrict__ bc)
{
    int k = blockIdx.x, t = threadIdx.x;  // 128 threads
    float4 vl = *(const float4*)&Wl[(size_t)k * 512 + t * 4];
    float4 vr = *(const float4*)&Wr[(size_t)k * 512 + t * 4];
    *(float4*)&Wc[(size_t)k * 1024 + t * 4] = vl;
    *(float4*)&Wc[(size_t)k * 1024 + 512 + t * 4] = vr;
    if (k == 0) {
        *(float4*)&bc[t * 4]       = *(const float4*)&bl[t * 4];
        *(float4*)&bc[512 + t * 4] = *(const float4*)&br[t * 4];
    }
}

// ---------------- CSR build ----------------
__global__ void count_edges(const int* __restrict__ dst, int E_in, int* __restrict__ cnt)
{
    int e = blockIdx.x * blockDim.x + threadIdx.x;
    if (e < E_in) atomicAdd(&cnt[dst[e]], 1);
}

__global__ void fill_edges(const int* __restrict__ src, const int* __restrict__ dst,
                           int E_in, int* __restrict__ next, int* __restrict__ csr)
{
    int e = blockIdx.x * blockDim.x + threadIdx.x;
    if (e < E_in) {
        int p = atomicAdd(&next[dst[e]], 1);
        csr[p] = src[e];
    }
}

__global__ __launch_bounds__(1024) void scan_excl(const int* __restrict__ cnt, int n,
                                                  int* __restrict__ off, int* __restrict__ next)
{
    __shared__ int bsum[1024];
    int t = threadIdx.x;
    int chunk = (n + 1023) >> 10;
    int lo = t * chunk, hi = min(n, lo + chunk);
    int s = 0;
    for (int i = lo; i < hi; ++i) s += cnt[i];
    bsum[t] = s;
    __syncthreads();
    for (int d = 1; d < 1024; d <<= 1) {
        int v = (t >= d) ? bsum[t - d] : 0;
        __syncthreads();
        bsum[t] += v;
        __syncthreads();
    }
    int run = t ? bsum[t - 1] : 0;
    for (int i = lo; i < hi; ++i) { off[i] = run; next[i] = run; run += cnt[i]; }
    if (t == 1023) off[n] = bsum[1023];
}

__global__ void remap_edges(const int* __restrict__ src, const int* __restrict__ dst,
                            int E_in, const int* __restrict__ nmap,
                            int* __restrict__ es2, int* __restrict__ ed2,
                            int* __restrict__ ec2, int* __restrict__ cnt2)
{
    int e = blockIdx.x * blockDim.x + threadIdx.x;
    if (e >= E_in) return;
    int ns = nmap[src[e]], nd = nmap[dst[e]];
    if (ns >= 0 && nd >= 0) {
        int pos = atomicAdd(ec2, 1);
        es2[pos] = ns; ed2[pos] = nd;
        atomicAdd(&cnt2[nd], 1);
    }
}

__global__ void fill_edges_dyn(const int* __restrict__ es, const int* __restrict__ ed,
                               const int* __restrict__ ec, int* __restrict__ next,
                               int* __restrict__ csr)
{
    int e = blockIdx.x * blockDim.x + threadIdx.x;
    if (e < *ec) {
        int p = atomicAdd(&next[ed[e]], 1);
        csr[p] = es[e];
    }
}

// ---------------- GATv2 aggregation: one wave per dst node ----------------
// XL/XR columns live in a combined [n,1024] buffer (ldx=1024).
__global__ __launch_bounds__(256) void gatv2_agg(
    const float* __restrict__ XL, const float* __restrict__ XR, int ldx,
    const int* __restrict__ csr_src, const int* __restrict__ off,
    const float* __restrict__ att, const float* __restrict__ bias,
    float* __restrict__ out, int n)
{
    // bijective XCD swizzle (gridDim.x divisible by 8 for our launches)
    int nwg = gridDim.x;
    int q = nwg >> 3;
    int swz = (blockIdx.x & 7) * q + (blockIdx.x >> 3);
    int wid = swz * 4 + (threadIdx.x >> 6);
    int lane = threadIdx.x & 63;
    if (wid >= n) return;
    const int f0 = lane * 8;  // flat (h,c) channel base; head = lane>>4
    float xr[8], atv[8], acc[8];
    {
        float4 r0 = *(const float4*)&XR[(size_t)wid * ldx + f0];
        float4 r1 = *(const float4*)&XR[(size_t)wid * ldx + f0 + 4];
        xr[0]=r0.x; xr[1]=r0.y; xr[2]=r0.z; xr[3]=r0.w;
        xr[4]=r1.x; xr[5]=r1.y; xr[6]=r1.z; xr[7]=r1.w;
        float4 t0 = *(const float4*)&att[f0];
        float4 t1 = *(const float4*)&att[f0 + 4];
        atv[0]=t0.x; atv[1]=t0.y; atv[2]=t0.z; atv[3]=t0.w;
        atv[4]=t1.x; atv[5]=t1.y; atv[6]=t1.z; atv[7]=t1.w;
#pragma unroll
        for (int j = 0; j < 8; ++j) acc[j] = 0.f;
    }
    float m = -INFINITY, ssum = 0.f;
    int e0 = off[wid], e1 = off[wid + 1];
    for (int e = e0 - 1; e < e1; ++e) {       // e==e0-1: self loop
        int s = (e < e0) ? wid : csr_src[e];
        float xl[8], part = 0.f;
        float4 l0 = *(const float4*)&XL[(size_t)s * ldx + f0];
        float4 l1 = *(const float4*)&XL[(size_t)s * ldx + f0 + 4];
        xl[0]=l0.x; xl[1]=l0.y; xl[2]=l0.z; xl[3]=l0.w;
        xl[4]=l1.x; xl[5]=l1.y; xl[6]=l1.z; xl[7]=l1.w;
#pragma unroll
        for (int j = 0; j < 8; ++j) {
            float v = xl[j] + xr[j];
            v = (v > 0.f) ? v : SLOPE * v;
            part += v * atv[j];
        }
        part += __shfl_xor(part, 1);
        part += __shfl_xor(part, 2);
        part += __shfl_xor(part, 4);
        part += __shfl_xor(part, 8);
        float mn = fmaxf(m, part);
        float scale = __expf(m - mn);
        float p = __expf(part - mn);
        ssum = ssum * scale + p;
#pragma unroll
        for (int j = 0; j < 8; ++j) acc[j] = acc[j] * scale + p * xl[j];
        m = mn;
    }
    float inv = 1.f / ssum;
#pragma unroll
    for (int j = 0; j < 8; ++j) {
        float v = acc[j] * inv;
        v += __shfl_xor(v, 16);
        v += __shfl_xor(v, 32);
        if (lane < 16) {
            int c = lane * 8 + j;
            float r = 0.25f * v + bias[c];
            out[(size_t)wid * 128 + c] = fmaxf(r, 0.f);
        }
    }
}

// ---------------- SAGE pooling score: one wave per node ----------------
__global__ __launch_bounds__(256) void sage_score(
    const float* __restrict__ X, const int* __restrict__ csr_src,
    const int* __restrict__ off, const float* __restrict__ Wn,
    const float* __restrict__ Wr, const float* __restrict__ bs,
    float* __restrict__ score, int n)
{
    int wid = (blockIdx.x * blockDim.x + threadIdx.x) >> 6;
    int lane = threadIdx.x & 63;
    if (wid >= n) return;
    int c0 = lane * 2;
    int e0 = off[wid], e1 = off[wid + 1];
    float a0 = 0.f, a1 = 0.f;
    for (int e = e0; e < e1; ++e) {
        int s = csr_src[e];
        float2 v = *(const float2*)&X[(size_t)s * 128 + c0];
        a0 += v.x; a1 += v.y;
    }
    float inv = 1.f / fmaxf((float)(e1 - e0), 1.f);
    float2 xv = *(const float2*)&X[(size_t)wid * 128 + c0];
    float part = a0 * inv * Wn[c0] + a1 * inv * Wn[c0 + 1] + xv.x * Wr[c0] + xv.y * Wr[c0 + 1];
#pragma unroll
    for (int sh = 1; sh < 64; sh <<= 1) part += __shfl_xor(part, sh);
    if (lane == 0) score[wid] = part + bs[0];
}

// ---------------- SAGPooling top-k: exact jax.lax.top_k rank ----------------
__global__ __launch_bounds__(512) void pool_rank(const float* __restrict__ score,
                                                 int npg, int k, int* __restrict__ nmap)
{
    __shared__ float s[512];
    int b = blockIdx.x, t = threadIdx.x;
    const float* sc = score + (size_t)b * npg;
    if (t < npg) s[t] = sc[t];
    __syncthreads();
    if (t < npg) {
        float mine = s[t];
        int rank = 0;
        for (int j = 0; j < npg; ++j) {
            float v = s[j];
            rank += (v > mine) || (v == mine && j < t);
        }
        nmap[(size_t)b * npg + t] = (rank < k) ? (b * k + rank) : -1;
    }
}

__global__ void pool_gather(const float* __restrict__ X, const float* __restrict__ score,
                            const int* __restrict__ nmap, float* __restrict__ Xn)
{
    int i = blockIdx.x, c = threadIdx.x;  // 128 threads
    int nid = nmap[i];
    if (nid < 0) return;
    float t = tanhf(score[i]);
    Xn[(size_t)nid * 128 + c] = X[(size_t)i * 128 + c] * t;
}

// ---------------- global max pool ----------------
__global__ void gmp(const float* __restrict__ X, int npg, float* __restrict__ out)
{
    int b = blockIdx.x, c = threadIdx.x;  // 128 threads
    const float* p = X + (size_t)b * npg * 128 + c;
    float m = -INFINITY;
    for (int i = 0; i < npg; ++i) m = fmaxf(m, p[(size_t)i * 128]);
    out[b * 128 + c] = m;
}

// ---------------- final: relu((x1+x2+x3) @ Wf + bf) ----------------
__global__ void final_mlp(const float* __restrict__ x1, const float* __restrict__ x2,
                          const float* __restrict__ x3, const float* __restrict__ Wf,
                          const float* __restrict__ bf, float* __restrict__ out)
{
    int b = blockIdx.x, o = threadIdx.x;  // 64 threads
    float acc = bf[o];
    for (int c = 0; c < 128; ++c) {
        float xv = x1[b * 128 + c] + x2[b * 128 + c] + x3[b * 128 + c];
        acc += xv * Wf[c * 64 + o];
    }
    out[b * 64 + o] = fmaxf(acc, 0.f);
}

// ---------------- host orchestration ----------------
static inline size_t alignup(size_t x) { return (x + 255) & ~(size_t)255; }

extern "C" void kernel_launch(void* const* d_in, const int* in_sizes, int n_in,
                              void* d_out, int out_size, void* d_ws, size_t ws_size,
                              hipStream_t stream)
{
    const float* x_feat = (const float*)d_in[0];
    const int*   ei     = (const int*)d_in[1];   // [2,E]: src then dst
    const float* Wl1  = (const float*)d_in[3];
    const float* bl1  = (const float*)d_in[4];
    const float* Wr1  = (const float*)d_in[5];
    const float* br1  = (const float*)d_in[6];
    const float* att1 = (const float*)d_in[7];
    const float* bias1= (const float*)d_in[8];
    const float* Wl2  = (const float*)d_in[9];
    const float* bl2  = (const float*)d_in[10];
    const float* Wr2  = (const float*)d_in[11];
    const float* br2  = (const float*)d_in[12];
    const float* att2 = (const float*)d_in[13];
    const float* bias2= (const float*)d_in[14];
    const float* Wsn  = (const float*)d_in[15];
    const float* Wsr  = (const float*)d_in[16];
    const float* bs   = (const float*)d_in[17];
    const float* Wf   = (const float*)d_in[18];
    const float* bf   = (const float*)d_in[19];
    float* out = (float*)d_out;

    const int* e_src = ei;
    const int* e_dst = ei + ETOT;

    // ---- workspace carve-up ----
    char* ws = (char*)d_ws;
    size_t o = 0;
    auto take = [&](size_t bytes) { size_t r = o; o = alignup(o + bytes); return r; };
    float* C1   = (float*)(ws + take((size_t)NTOT * 1024 * 4));  // [n,1024] = XL|XR (reused layer 2)
    float* H1   = (float*)(ws + take((size_t)NTOT * 128 * 4));
    float* PX   = (float*)(ws + take((size_t)N2 * 128 * 4));
    float* H2   = (float*)(ws + take((size_t)N2 * 128 * 4));
    float* P2X  = (float*)(ws + take((size_t)N3 * 128 * 4));
    float* Wc1  = (float*)(ws + take((size_t)512 * 1024 * 4));
    float* bc1  = (float*)(ws + take(1024 * 4));
    float* Wc2  = (float*)(ws + take((size_t)128 * 1024 * 4));
    float* bc2  = (float*)(ws + take(1024 * 4));
    float* score= (float*)(ws + take((size_t)NTOT * 4));
    int*   nmap = (int*)(ws + take((size_t)NTOT * 4));
    int*   cnt  = (int*)(ws + take((size_t)(NTOT + 1) * 4));
    int*   offs = (int*)(ws + take((size_t)(NTOT + 1) * 4));
    int*   nxt  = (int*)(ws + take((size_t)(NTOT + 1) * 4));
    int*   csr1 = (int*)(ws + take((size_t)ETOT * 4));
    int*   es2  = (int*)(ws + take((size_t)ETOT * 4));
    int*   ed2  = (int*)(ws + take((size_t)ETOT * 4));
    int*   csr2 = (int*)(ws + take((size_t)ETOT * 4));
    int*   ec2  = (int*)(ws + take(256));
    float* x1g  = (float*)(ws + take((size_t)NB * 128 * 4));
    float* x2g  = (float*)(ws + take((size_t)NB * 128 * 4));
    float* x3g  = (float*)(ws + take((size_t)NB * 128 * 4));
    (void)ws_size; (void)in_sizes; (void)n_in; (void)out_size;

    // ---- concat weights, then one fused N=1024 GEMM per layer ----
    concat_wb<<<512, 128, 0, stream>>>(Wl1, Wr1, bl1, br1, Wc1, bc1);
    concat_wb<<<128, 128, 0, stream>>>(Wl2, Wr2, bl2, br2, Wc2, bc2);

    // ---- layer 1 transform: C1 = x_feat @ [Wl1|Wr1] + [bl1|br1] ----
    sgemm_bias<<<dim3(1024 / BN, NTOT / BM), 256, 0, stream>>>(x_feat, Wc1, bc1, C1, NTOT, 1024, 512);

    // ---- CSR (by dst) of the input graph ----
    hipMemsetAsync(cnt, 0, (size_t)(NTOT + 1) * 4, stream);
    count_edges<<<ETOT / 256, 256, 0, stream>>>(e_dst, ETOT, cnt);
    scan_excl<<<1, 1024, 0, stream>>>(cnt, NTOT, offs, nxt);
    fill_edges<<<ETOT / 256, 256, 0, stream>>>(e_src, e_dst, ETOT, nxt, csr1);

    // ---- GATv2 layer 1 + relu -> H1 ----
    gatv2_agg<<<NTOT / 4, 256, 0, stream>>>(C1, C1 + 512, 1024, csr1, offs, att1, bias1, H1, NTOT);

    // ---- x1 = gmp(H1) ----
    gmp<<<NB, 128, 0, stream>>>(H1, NPG, x1g);

    // ---- SAGE score 1 + pool 1 ----
    sage_score<<<NTOT / 4, 256, 0, stream>>>(H1, csr1, offs, Wsn, Wsr, bs, score, NTOT);
    pool_rank<<<NB, 512, 0, stream>>>(score, NPG, K1, nmap);
    pool_gather<<<NTOT, 128, 0, stream>>>(H1, score, nmap, PX);

    // ---- x2 = gmp(PX) ----
    gmp<<<NB, 128, 0, stream>>>(PX, K1, x2g);

    // ---- remap + compact edges, CSR2 ----
    hipMemsetAsync(cnt, 0, (size_t)(NTOT + 1) * 4, stream);
    hipMemsetAsync(ec2, 0, 4, stream);
    remap_edges<<<ETOT / 256, 256, 0, stream>>>(e_src, e_dst, ETOT, nmap, es2, ed2, ec2, cnt);
    scan_excl<<<1, 1024, 0, stream>>>(cnt, N2, offs, nxt);
    fill_edges_dyn<<<ETOT / 256, 256, 0, stream>>>(es2, ed2, ec2, nxt, csr2);

    // ---- layer 2 transform: C1 = PX @ [Wl2|Wr2] + [bl2|br2] (K=128) ----
    sgemm_bias<<<dim3(1024 / BN, N2 / BM), 256, 0, stream>>>(PX, Wc2, bc2, C1, N2, 1024, 128);

    // ---- GATv2 layer 2 + relu -> H2 ----
    gatv2_agg<<<(N2 + 3) / 4, 256, 0, stream>>>(C1, C1 + 512, 1024, csr2, offs, att2, bias2, H2, N2);

    // ---- SAGE score 2 + pool 2 ----
    sage_score<<<(N2 + 3) / 4, 256, 0, stream>>>(H2, csr2, offs, Wsn, Wsr, bs, score, N2);
    pool_rank<<<NB, 512, 0, stream>>>(score, K1, K2, nmap);
    pool_gather<<<N2, 128, 0, stream>>>(H2, score, nmap, P2X);

    // ---- x3 = gmp(P2X) ----
    gmp<<<NB, 128, 0, stream>>>(P2X, K2, x3g);

    // ---- final MLP ----
    final_mlp<<<NB, 64, 0, stream>>>(x1g, x2g, x3g, Wf, bf, out);
}

// Round 3
// 563.641 us; speedup vs baseline: 1.2393x; 1.1519x over previous
//
#include <hip/hip_runtime.h>
#include <hip/hip_bf16.h>
#include <math.h>

// ---------------- problem constants ----------------
#define NB    32          // graphs
#define NPG   512         // nodes per graph
#define NTOT  (NB*NPG)    // 16384
#define EPG   4096
#define ETOT  (NB*EPG)    // 131072
#define K1    308
#define K2    185
#define N2    (NB*K1)     // 9856
#define N3    (NB*K2)     // 5920
#define SLOPE 0.2f

typedef _Float16 f16;
typedef f16   f16x8 __attribute__((ext_vector_type(8)));
typedef float f32x4 __attribute__((ext_vector_type(4)));

// W pre-scale (power of 2, exact) keeps lo-split in fp16 normal range
#define WSCALE 512.0f
#define WINV   (1.0f/512.0f)

// async global->LDS, 16B per lane, wave-uniform LDS base
__device__ __forceinline__ void gll16(const void* g, void* l)
{
    __builtin_amdgcn_global_load_lds(
        (const __attribute__((address_space(1))) unsigned int*)g,
        (__attribute__((address_space(3))) unsigned int*)l, 16, 0, 0);
}

// ---------------- split fp32 -> (hi,lo) fp16 ----------------
__global__ __launch_bounds__(256) void split_a(const float* __restrict__ A,
                                               f16* __restrict__ Ah, f16* __restrict__ Al,
                                               int n8)
{
    int i = blockIdx.x * 256 + threadIdx.x;   // 8 floats per thread
    if (i >= n8) return;
    const float4* p = (const float4*)(A + (size_t)i * 8);
    float4 v0 = p[0], v1 = p[1];
    float v[8] = {v0.x, v0.y, v0.z, v0.w, v1.x, v1.y, v1.z, v1.w};
    f16x8 h, l;
#pragma unroll
    for (int j = 0; j < 8; ++j) {
        f16 hh = (f16)v[j];
        h[j] = hh;
        l[j] = (f16)(v[j] - (float)hh);
    }
    *(f16x8*)(Ah + (size_t)i * 8) = h;
    *(f16x8*)(Al + (size_t)i * 8) = l;
}

// ---------------- W prep: concat L|R, transpose to [1024][K], scale, split ----------------
__global__ __launch_bounds__(256) void prep_w(const float* __restrict__ WL,
                                              const float* __restrict__ WR,
                                              f16* __restrict__ Wh, f16* __restrict__ Wlo,
                                              int K)
{
    __shared__ float t[32][33];
    int bk = blockIdx.x;          // k tile (K/32)
    int bn = blockIdx.y;          // n tile (32 tiles of 32 over 1024)
    int tx = threadIdx.x & 31, ty = threadIdx.x >> 5;   // 32 x 8
    const float* Wsrc = (bn < 16) ? WL : WR;
    int ncol = bn * 32 - (bn < 16 ? 0 : 512) + tx;
#pragma unroll
    for (int q = 0; q < 4; ++q) {
        int kk = bk * 32 + ty + q * 8;
        t[ty + q * 8][tx] = Wsrc[(size_t)kk * 512 + ncol];
    }
    __syncthreads();
#pragma unroll
    for (int q = 0; q < 4; ++q) {
        int n = bn * 32 + ty + q * 8;
        int k = bk * 32 + tx;
        float v = t[tx][ty + q * 8] * WSCALE;
        f16 h = (f16)v;
        Wh [(size_t)n * K + k] = h;
        Wlo[(size_t)n * K + k] = (f16)(v - (float)h);
    }
}

// ---------------- split-fp16 MFMA GEMM ----------------
// C[M,1024] = (Ah+Al)[M,K] @ (Wh+Wlo)^T[K,1024] * WINV + bias(l|r)
// A: [M][K] f16 row-major (hi,lo). B: [1024][K] f16 row-major (= W transposed).
// block: 256 thr / 4 waves; tile 128x128; BK=32; wave w owns 64x64 quadrant.
__global__ __launch_bounds__(256) void gemm_split(
    const f16* __restrict__ Ah, const f16* __restrict__ Al,
    const f16* __restrict__ Bh, const f16* __restrict__ Bl,
    const float* __restrict__ bias_l, const float* __restrict__ bias_r,
    float* __restrict__ C, int M, int K)
{
    __shared__ f16 sm[4][4][128][8];   // [mat: Ah,Al,Bh,Bl][kblk][row][8k] = 32 KB
    const int Nn = 1024;
    int tid = threadIdx.x;
    int wave = tid >> 6, lane = tid & 63;
    int row0 = blockIdx.y * 128, col0 = blockIdx.x * 128;

    const f16* base = (wave == 0) ? Ah : (wave == 1) ? Al : (wave == 2) ? Bh : Bl;
    int rc0 = (wave < 2) ? row0 : col0;

    int wr = wave >> 1, wc = wave & 1;
    int r16 = lane & 15, kb = lane >> 4;

    f32x4 acc[4][4] = {};
    for (int kt = 0; kt < K; kt += 32) {
        // stage: wave w loads matrix w (8 chunks of 64 rows x 8 k)
#pragma unroll
        for (int i = 0; i < 8; ++i) {
            int kblk = i >> 1, rh = i & 1;
            const f16* src = base + (size_t)(rc0 + rh * 64 + lane) * K + kt + kblk * 8;
            gll16(src, &sm[wave][kblk][rh * 64][0]);
        }
        __syncthreads();

        f16x8 ah[4], al[4], bh[4], bl[4];
#pragma unroll
        for (int m = 0; m < 4; ++m) {
            ah[m] = *(const f16x8*)&sm[0][kb][wr * 64 + m * 16 + r16][0];
            al[m] = *(const f16x8*)&sm[1][kb][wr * 64 + m * 16 + r16][0];
        }
#pragma unroll
        for (int n = 0; n < 4; ++n) {
            bh[n] = *(const f16x8*)&sm[2][kb][wc * 64 + n * 16 + r16][0];
            bl[n] = *(const f16x8*)&sm[3][kb][wc * 64 + n * 16 + r16][0];
        }
#pragma unroll
        for (int m = 0; m < 4; ++m)
#pragma unroll
            for (int n = 0; n < 4; ++n) {
                acc[m][n] = __builtin_amdgcn_mfma_f32_16x16x32_f16(ah[m], bh[n], acc[m][n], 0, 0, 0);
                acc[m][n] = __builtin_amdgcn_mfma_f32_16x16x32_f16(ah[m], bl[n], acc[m][n], 0, 0, 0);
                acc[m][n] = __builtin_amdgcn_mfma_f32_16x16x32_f16(al[m], bh[n], acc[m][n], 0, 0, 0);
            }
        __syncthreads();
    }
    // epilogue: C/D frag: col = lane&15, row = (lane>>4)*4 + j
#pragma unroll
    for (int m = 0; m < 4; ++m)
#pragma unroll
        for (int n = 0; n < 4; ++n) {
            int cc = col0 + wc * 64 + n * 16 + r16;
            float b = (cc < 512) ? bias_l[cc] : bias_r[cc - 512];
#pragma unroll
            for (int j = 0; j < 4; ++j) {
                int rr = row0 + wr * 64 + m * 16 + kb * 4 + j;
                C[(size_t)rr * Nn + cc] = acc[m][n][j] * WINV + b;
            }
        }
}

// ---------------- CSR build ----------------
__global__ void count_edges(const int* __restrict__ dst, int E_in, int* __restrict__ cnt)
{
    int e = blockIdx.x * blockDim.x + threadIdx.x;
    if (e < E_in) atomicAdd(&cnt[dst[e]], 1);
}

__global__ void fill_edges(const int* __restrict__ src, const int* __restrict__ dst,
                           int E_in, int* __restrict__ next, int* __restrict__ csr)
{
    int e = blockIdx.x * blockDim.x + threadIdx.x;
    if (e < E_in) {
        int p = atomicAdd(&next[dst[e]], 1);
        csr[p] = src[e];
    }
}

__global__ __launch_bounds__(1024) void scan_excl(const int* __restrict__ cnt, int n,
                                                  int* __restrict__ off, int* __restrict__ next)
{
    __shared__ int bsum[1024];
    int t = threadIdx.x;
    int chunk = (n + 1023) >> 10;
    int lo = t * chunk, hi = min(n, lo + chunk);
    int s = 0;
    for (int i = lo; i < hi; ++i) s += cnt[i];
    bsum[t] = s;
    __syncthreads();
    for (int d = 1; d < 1024; d <<= 1) {
        int v = (t >= d) ? bsum[t - d] : 0;
        __syncthreads();
        bsum[t] += v;
        __syncthreads();
    }
    int run = t ? bsum[t - 1] : 0;
    for (int i = lo; i < hi; ++i) { off[i] = run; next[i] = run; run += cnt[i]; }
    if (t == 1023) off[n] = bsum[1023];
}

__global__ void remap_edges(const int* __restrict__ src, const int* __restrict__ dst,
                            int E_in, const int* __restrict__ nmap,
                            int* __restrict__ es2, int* __restrict__ ed2,
                            int* __restrict__ ec2, int* __restrict__ cnt2)
{
    int e = blockIdx.x * blockDim.x + threadIdx.x;
    if (e >= E_in) return;
    int ns = nmap[src[e]], nd = nmap[dst[e]];
    if (ns >= 0 && nd >= 0) {
        int pos = atomicAdd(ec2, 1);
        es2[pos] = ns; ed2[pos] = nd;
        atomicAdd(&cnt2[nd], 1);
    }
}

__global__ void fill_edges_dyn(const int* __restrict__ es, const int* __restrict__ ed,
                               const int* __restrict__ ec, int* __restrict__ next,
                               int* __restrict__ csr)
{
    int e = blockIdx.x * blockDim.x + threadIdx.x;
    if (e < *ec) {
        int p = atomicAdd(&next[ed[e]], 1);
        csr[p] = es[e];
    }
}

// ---------------- GATv2 aggregation: one wave per dst node ----------------
__global__ __launch_bounds__(256) void gatv2_agg(
    const float* __restrict__ XL, const float* __restrict__ XR, int ldx,
    const int* __restrict__ csr_src, const int* __restrict__ off,
    const float* __restrict__ att, const float* __restrict__ bias,
    float* __restrict__ out, int n)
{
    int nwg = gridDim.x;
    int q = nwg >> 3;
    int swz = (blockIdx.x & 7) * q + (blockIdx.x >> 3);
    int wid = swz * 4 + (threadIdx.x >> 6);
    int lane = threadIdx.x & 63;
    if (wid >= n) return;
    const int f0 = lane * 8;
    float xr[8], atv[8], acc[8];
    {
        float4 r0 = *(const float4*)&XR[(size_t)wid * ldx + f0];
        float4 r1 = *(const float4*)&XR[(size_t)wid * ldx + f0 + 4];
        xr[0]=r0.x; xr[1]=r0.y; xr[2]=r0.z; xr[3]=r0.w;
        xr[4]=r1.x; xr[5]=r1.y; xr[6]=r1.z; xr[7]=r1.w;
        float4 t0 = *(const float4*)&att[f0];
        float4 t1 = *(const float4*)&att[f0 + 4];
        atv[0]=t0.x; atv[1]=t0.y; atv[2]=t0.z; atv[3]=t0.w;
        atv[4]=t1.x; atv[5]=t1.y; atv[6]=t1.z; atv[7]=t1.w;
#pragma unroll
        for (int j = 0; j < 8; ++j) acc[j] = 0.f;
    }
    float m = -INFINITY, ssum = 0.f;
    int e0 = off[wid], e1 = off[wid + 1];
    for (int e = e0 - 1; e < e1; ++e) {
        int s = (e < e0) ? wid : csr_src[e];
        float xl[8], part = 0.f;
        float4 l0 = *(const float4*)&XL[(size_t)s * ldx + f0];
        float4 l1 = *(const float4*)&XL[(size_t)s * ldx + f0 + 4];
        xl[0]=l0.x; xl[1]=l0.y; xl[2]=l0.z; xl[3]=l0.w;
        xl[4]=l1.x; xl[5]=l1.y; xl[6]=l1.z; xl[7]=l1.w;
#pragma unroll
        for (int j = 0; j < 8; ++j) {
            float v = xl[j] + xr[j];
            v = (v > 0.f) ? v : SLOPE * v;
            part += v * atv[j];
        }
        part += __shfl_xor(part, 1);
        part += __shfl_xor(part, 2);
        part += __shfl_xor(part, 4);
        part += __shfl_xor(part, 8);
        float mn = fmaxf(m, part);
        float scale = __expf(m - mn);
        float p = __expf(part - mn);
        ssum = ssum * scale + p;
#pragma unroll
        for (int j = 0; j < 8; ++j) acc[j] = acc[j] * scale + p * xl[j];
        m = mn;
    }
    float inv = 1.f / ssum;
#pragma unroll
    for (int j = 0; j < 8; ++j) {
        float v = acc[j] * inv;
        v += __shfl_xor(v, 16);
        v += __shfl_xor(v, 32);
        if (lane < 16) {
            int c = lane * 8 + j;
            float r = 0.25f * v + bias[c];
            out[(size_t)wid * 128 + c] = fmaxf(r, 0.f);
        }
    }
}

// ---------------- SAGE pooling score ----------------
__global__ __launch_bounds__(256) void sage_score(
    const float* __restrict__ X, const int* __restrict__ csr_src,
    const int* __restrict__ off, const float* __restrict__ Wn,
    const float* __restrict__ Wr, const float* __restrict__ bs,
    float* __restrict__ score, int n)
{
    int wid = (blockIdx.x * blockDim.x + threadIdx.x) >> 6;
    int lane = threadIdx.x & 63;
    if (wid >= n) return;
    int c0 = lane * 2;
    int e0 = off[wid], e1 = off[wid + 1];
    float a0 = 0.f, a1 = 0.f;
    for (int e = e0; e < e1; ++e) {
        int s = csr_src[e];
        float2 v = *(const float2*)&X[(size_t)s * 128 + c0];
        a0 += v.x; a1 += v.y;
    }
    float inv = 1.f / fmaxf((float)(e1 - e0), 1.f);
    float2 xv = *(const float2*)&X[(size_t)wid * 128 + c0];
    float part = a0 * inv * Wn[c0] + a1 * inv * Wn[c0 + 1] + xv.x * Wr[c0] + xv.y * Wr[c0 + 1];
#pragma unroll
    for (int sh = 1; sh < 64; sh <<= 1) part += __shfl_xor(part, sh);
    if (lane == 0) score[wid] = part + bs[0];
}

// ---------------- SAGPooling top-k (exact jax.lax.top_k rank) ----------------
__global__ __launch_bounds__(512) void pool_rank(const float* __restrict__ score,
                                                 int npg, int k, int* __restrict__ nmap)
{
    __shared__ float s[512];
    int b = blockIdx.x, t = threadIdx.x;
    const float* sc = score + (size_t)b * npg;
    if (t < npg) s[t] = sc[t];
    __syncthreads();
    if (t < npg) {
        float mine = s[t];
        int rank = 0;
        for (int j = 0; j < npg; ++j) {
            float v = s[j];
            rank += (v > mine) || (v == mine && j < t);
        }
        nmap[(size_t)b * npg + t] = (rank < k) ? (b * k + rank) : -1;
    }
}

// gather + tanh gate; optionally emit fp16 split for the next GEMM
__global__ void pool_gather(const float* __restrict__ X, const float* __restrict__ score,
                            const int* __restrict__ nmap, float* __restrict__ Xn,
                            f16* __restrict__ Xh, f16* __restrict__ Xl)
{
    int i = blockIdx.x, c = threadIdx.x;  // 128 threads
    int nid = nmap[i];
    if (nid < 0) return;
    float t = tanhf(score[i]);
    float v = X[(size_t)i * 128 + c] * t;
    Xn[(size_t)nid * 128 + c] = v;
    if (Xh) {
        f16 h = (f16)v;
        Xh[(size_t)nid * 128 + c] = h;
        Xl[(size_t)nid * 128 + c] = (f16)(v - (float)h);
    }
}

// ---------------- global max pool ----------------
__global__ void gmp(const float* __restrict__ X, int npg, float* __restrict__ out)
{
    int b = blockIdx.x, c = threadIdx.x;  // 128 threads
    const float* p = X + (size_t)b * npg * 128 + c;
    float m = -INFINITY;
    for (int i = 0; i < npg; ++i) m = fmaxf(m, p[(size_t)i * 128]);
    out[b * 128 + c] = m;
}

// ---------------- final: relu((x1+x2+x3) @ Wf + bf) ----------------
__global__ void final_mlp(const float* __restrict__ x1, const float* __restrict__ x2,
                          const float* __restrict__ x3, const float* __restrict__ Wf,
                          const float* __restrict__ bf, float* __restrict__ out)
{
    int b = blockIdx.x, o = threadIdx.x;  // 64 threads
    float acc = bf[o];
    for (int c = 0; c < 128; ++c) {
        float xv = x1[b * 128 + c] + x2[b * 128 + c] + x3[b * 128 + c];
        acc += xv * Wf[c * 64 + o];
    }
    out[b * 64 + o] = fmaxf(acc, 0.f);
}

// ---------------- host orchestration ----------------
static inline size_t alignup(size_t x) { return (x + 255) & ~(size_t)255; }

extern "C" void kernel_launch(void* const* d_in, const int* in_sizes, int n_in,
                              void* d_out, int out_size, void* d_ws, size_t ws_size,
                              hipStream_t stream)
{
    const float* x_feat = (const float*)d_in[0];
    const int*   ei     = (const int*)d_in[1];
    const float* Wl1  = (const float*)d_in[3];
    const float* bl1  = (const float*)d_in[4];
    const float* Wr1  = (const float*)d_in[5];
    const float* br1  = (const float*)d_in[6];
    const float* att1 = (const float*)d_in[7];
    const float* bias1= (const float*)d_in[8];
    const float* Wl2  = (const float*)d_in[9];
    const float* bl2  = (const float*)d_in[10];
    const float* Wr2  = (const float*)d_in[11];
    const float* br2  = (const float*)d_in[12];
    const float* att2 = (const float*)d_in[13];
    const float* bias2= (const float*)d_in[14];
    const float* Wsn  = (const float*)d_in[15];
    const float* Wsr  = (const float*)d_in[16];
    const float* bs   = (const float*)d_in[17];
    const float* Wf   = (const float*)d_in[18];
    const float* bf   = (const float*)d_in[19];
    float* out = (float*)d_out;

    const int* e_src = ei;
    const int* e_dst = ei + ETOT;

    // ---- workspace carve-up ----
    char* ws = (char*)d_ws;
    size_t o = 0;
    auto take = [&](size_t bytes) { size_t r = o; o = alignup(o + bytes); return r; };
    float* C1   = (float*)(ws + take((size_t)NTOT * 1024 * 4));  // XL|XR fp32 (both layers)
    float* H1   = (float*)(ws + take((size_t)NTOT * 128 * 4));
    float* PX   = (float*)(ws + take((size_t)N2 * 128 * 4));
    float* H2   = (float*)(ws + take((size_t)N2 * 128 * 4));
    float* P2X  = (float*)(ws + take((size_t)N3 * 128 * 4));
    f16*   Ah1  = (f16*)(ws + take((size_t)NTOT * 512 * 2));
    f16*   Al1  = (f16*)(ws + take((size_t)NTOT * 512 * 2));
    f16*   Wh1  = (f16*)(ws + take((size_t)1024 * 512 * 2));
    f16*   Wo1  = (f16*)(ws + take((size_t)1024 * 512 * 2));
    f16*   Wh2  = (f16*)(ws + take((size_t)1024 * 128 * 2));
    f16*   Wo2  = (f16*)(ws + take((size_t)1024 * 128 * 2));
    f16*   PXh  = (f16*)(ws + take((size_t)N2 * 128 * 2));
    f16*   PXl  = (f16*)(ws + take((size_t)N2 * 128 * 2));
    float* score= (float*)(ws + take((size_t)NTOT * 4));
    int*   nmap = (int*)(ws + take((size_t)NTOT * 4));
    int*   cnt  = (int*)(ws + take((size_t)(NTOT + 1) * 4));
    int*   offs = (int*)(ws + take((size_t)(NTOT + 1) * 4));
    int*   nxt  = (int*)(ws + take((size_t)(NTOT + 1) * 4));
    int*   csr1 = (int*)(ws + take((size_t)ETOT * 4));
    int*   es2  = (int*)(ws + take((size_t)ETOT * 4));
    int*   ed2  = (int*)(ws + take((size_t)ETOT * 4));
    int*   csr2 = (int*)(ws + take((size_t)ETOT * 4));
    int*   ec2  = (int*)(ws + take(256));
    float* x1g  = (float*)(ws + take((size_t)NB * 128 * 4));
    float* x2g  = (float*)(ws + take((size_t)NB * 128 * 4));
    float* x3g  = (float*)(ws + take((size_t)NB * 128 * 4));
    (void)ws_size; (void)in_sizes; (void)n_in; (void)out_size;

    // ---- prep: split x_feat, transpose+split weights ----
    split_a<<<(NTOT * 512 / 8) / 256, 256, 0, stream>>>(x_feat, Ah1, Al1, NTOT * 512 / 8);
    prep_w<<<dim3(512 / 32, 32), 256, 0, stream>>>(Wl1, Wr1, Wh1, Wo1, 512);
    prep_w<<<dim3(128 / 32, 32), 256, 0, stream>>>(Wl2, Wr2, Wh2, Wo2, 128);

    // ---- layer 1 transform: C1 = x @ [Wl1|Wr1] + [bl1|br1]  (split-fp16 MFMA) ----
    gemm_split<<<dim3(8, NTOT / 128), 256, 0, stream>>>(Ah1, Al1, Wh1, Wo1, bl1, br1, C1, NTOT, 512);

    // ---- CSR (by dst) ----
    hipMemsetAsync(cnt, 0, (size_t)(NTOT + 1) * 4, stream);
    count_edges<<<ETOT / 256, 256, 0, stream>>>(e_dst, ETOT, cnt);
    scan_excl<<<1, 1024, 0, stream>>>(cnt, NTOT, offs, nxt);
    fill_edges<<<ETOT / 256, 256, 0, stream>>>(e_src, e_dst, ETOT, nxt, csr1);

    // ---- GATv2 layer 1 + relu -> H1 ----
    gatv2_agg<<<NTOT / 4, 256, 0, stream>>>(C1, C1 + 512, 1024, csr1, offs, att1, bias1, H1, NTOT);
    gmp<<<NB, 128, 0, stream>>>(H1, NPG, x1g);

    // ---- SAGE score 1 + pool 1 (emits fp16 split of PX) ----
    sage_score<<<NTOT / 4, 256, 0, stream>>>(H1, csr1, offs, Wsn, Wsr, bs, score, NTOT);
    pool_rank<<<NB, 512, 0, stream>>>(score, NPG, K1, nmap);
    pool_gather<<<NTOT, 128, 0, stream>>>(H1, score, nmap, PX, PXh, PXl);
    gmp<<<NB, 128, 0, stream>>>(PX, K1, x2g);

    // ---- remap + compact edges, CSR2 ----
    hipMemsetAsync(cnt, 0, (size_t)(NTOT + 1) * 4, stream);
    hipMemsetAsync(ec2, 0, 4, stream);
    remap_edges<<<ETOT / 256, 256, 0, stream>>>(e_src, e_dst, ETOT, nmap, es2, ed2, ec2, cnt);
    scan_excl<<<1, 1024, 0, stream>>>(cnt, N2, offs, nxt);
    fill_edges_dyn<<<ETOT / 256, 256, 0, stream>>>(es2, ed2, ec2, nxt, csr2);

    // ---- layer 2 transform: C1 = PX @ [Wl2|Wr2] + [bl2|br2]  (K=128) ----
    gemm_split<<<dim3(8, N2 / 128), 256, 0, stream>>>(PXh, PXl, Wh2, Wo2, bl2, br2, C1, N2, 128);

    // ---- GATv2 layer 2 + relu -> H2 ----
    gatv2_agg<<<(N2 + 3) / 4, 256, 0, stream>>>(C1, C1 + 512, 1024, csr2, offs, att2, bias2, H2, N2);

    // ---- SAGE score 2 + pool 2 ----
    sage_score<<<(N2 + 3) / 4, 256, 0, stream>>>(H2, csr2, offs, Wsn, Wsr, bs, score, N2);
    pool_rank<<<NB, 512, 0, stream>>>(score, K1, K2, nmap);
    pool_gather<<<N2, 128, 0, stream>>>(H2, score, nmap, P2X, (f16*)nullptr, (f16*)nullptr);
    gmp<<<NB, 128, 0, stream>>>(P2X, K2, x3g);

    // ---- final MLP ----
    final_mlp<<<NB, 64, 0, stream>>>(x1g, x2g, x3g, Wf, bf, out);
}

// Round 4
// 464.115 us; speedup vs baseline: 1.5051x; 1.2144x over previous
//
#include <hip/hip_runtime.h>
#include <hip/hip_bf16.h>
#include <math.h>

// ---------------- problem constants ----------------
#define NB    32          // graphs
#define NPG   512         // nodes per graph
#define NTOT  (NB*NPG)    // 16384
#define EPG   4096
#define ETOT  (NB*EPG)    // 131072
#define K1    308
#define K2    185
#define N2    (NB*K1)     // 9856
#define N3    (NB*K2)     // 5920
#define SLOPE 0.2f

typedef _Float16 f16;
typedef f16   f16x8 __attribute__((ext_vector_type(8)));
typedef float f32x4 __attribute__((ext_vector_type(4)));

// W pre-scale (power of 2, exact) keeps lo-split in fp16 normal range
#define WSCALE 512.0f
#define WINV   (1.0f/512.0f)

// monotone float <-> uint encoding (total order preserved); enc(x) > 0 for all finite x
__device__ __forceinline__ unsigned enc_f(float v) {
    unsigned u = __float_as_uint(v);
    return (u & 0x80000000u) ? ~u : (u | 0x80000000u);
}
__device__ __forceinline__ float dec_f(unsigned e) {
    return (e & 0x80000000u) ? __uint_as_float(e ^ 0x80000000u) : __uint_as_float(~e);
}

// async global->LDS, 16B per lane, wave-uniform LDS base
__device__ __forceinline__ void gll16(const void* g, void* l)
{
    __builtin_amdgcn_global_load_lds(
        (const __attribute__((address_space(1))) unsigned int*)g,
        (__attribute__((address_space(3))) unsigned int*)l, 16, 0, 0);
}

// ---------------- split fp32 -> (hi,lo) fp16 ----------------
__global__ __launch_bounds__(256) void split_a(const float* __restrict__ A,
                                               f16* __restrict__ Ah, f16* __restrict__ Al,
                                               int n8)
{
    int i = blockIdx.x * 256 + threadIdx.x;   // 8 floats per thread
    if (i >= n8) return;
    const float4* p = (const float4*)(A + (size_t)i * 8);
    float4 v0 = p[0], v1 = p[1];
    float v[8] = {v0.x, v0.y, v0.z, v0.w, v1.x, v1.y, v1.z, v1.w};
    f16x8 h, l;
#pragma unroll
    for (int j = 0; j < 8; ++j) {
        f16 hh = (f16)v[j];
        h[j] = hh;
        l[j] = (f16)(v[j] - (float)hh);
    }
    *(f16x8*)(Ah + (size_t)i * 8) = h;
    *(f16x8*)(Al + (size_t)i * 8) = l;
}

// ---------------- W prep: concat L|R, transpose to [1024][K], scale, split ----------------
__global__ __launch_bounds__(256) void prep_w(const float* __restrict__ WL,
                                              const float* __restrict__ WR,
                                              f16* __restrict__ Wh, f16* __restrict__ Wlo,
                                              int K)
{
    __shared__ float t[32][33];
    int bk = blockIdx.x;          // k tile (K/32)
    int bn = blockIdx.y;          // n tile (32 tiles of 32 over 1024)
    int tx = threadIdx.x & 31, ty = threadIdx.x >> 5;   // 32 x 8
    const float* Wsrc = (bn < 16) ? WL : WR;
    int ncol = bn * 32 - (bn < 16 ? 0 : 512) + tx;
#pragma unroll
    for (int q = 0; q < 4; ++q) {
        int kk = bk * 32 + ty + q * 8;
        t[ty + q * 8][tx] = Wsrc[(size_t)kk * 512 + ncol];
    }
    __syncthreads();
#pragma unroll
    for (int q = 0; q < 4; ++q) {
        int n = bn * 32 + ty + q * 8;
        int k = bk * 32 + tx;
        float v = t[tx][ty + q * 8] * WSCALE;
        f16 h = (f16)v;
        Wh [(size_t)n * K + k] = h;
        Wlo[(size_t)n * K + k] = (f16)(v - (float)h);
    }
}

// ---------------- split-fp16 MFMA GEMM (double-buffered, 2-phase pipeline) ----------------
// C[M,1024] = (Ah+Al)[M,K] @ (Wh+Wlo)^T[K,1024] * WINV + bias(l|r)
// block: 256 thr / 4 waves; tile 128x128; BK=32; wave w owns 64x64 quadrant.
__global__ __launch_bounds__(256) void gemm_split(
    const f16* __restrict__ Ah, const f16* __restrict__ Al,
    const f16* __restrict__ Bh, const f16* __restrict__ Bl,
    const float* __restrict__ bias_l, const float* __restrict__ bias_r,
    float* __restrict__ C, int M, int K)
{
    __shared__ f16 sm[2][4][4][128][8];   // [dbuf][mat: Ah,Al,Bh,Bl][kblk][row][8k] = 64 KB
    const int Nn = 1024;
    int tid = threadIdx.x;
    int wave = tid >> 6, lane = tid & 63;
    int row0 = blockIdx.y * 128, col0 = blockIdx.x * 128;

    const f16* base = (wave == 0) ? Ah : (wave == 1) ? Al : (wave == 2) ? Bh : Bl;
    int rc0 = (wave < 2) ? row0 : col0;

    int wr = wave >> 1, wc = wave & 1;
    int r16 = lane & 15, kb = lane >> 4;

    const int nt = K >> 5;   // K/32 tiles

    // stage K-tile t into buffer buf (wave w loads matrix w: 8 chunks of 64 rows x 8 k)
    auto stage = [&](int buf, int t) {
#pragma unroll
        for (int i = 0; i < 8; ++i) {
            int kblk = i >> 1, rh = i & 1;
            const f16* src = base + (size_t)(rc0 + rh * 64 + lane) * K + t * 32 + kblk * 8;
            gll16(src, &sm[buf][wave][kblk][rh * 64][0]);
        }
    };

    f32x4 acc[4][4] = {};
    int cur = 0;
    stage(0, 0);
    __syncthreads();

    for (int t = 0; t < nt; ++t) {
        if (t + 1 < nt) stage(cur ^ 1, t + 1);   // prefetch next tile (in flight during MFMA)

        f16x8 ah[4], al[4], bh[4], bl[4];
#pragma unroll
        for (int m = 0; m < 4; ++m) {
            ah[m] = *(const f16x8*)&sm[cur][0][kb][wr * 64 + m * 16 + r16][0];
            al[m] = *(const f16x8*)&sm[cur][1][kb][wr * 64 + m * 16 + r16][0];
        }
#pragma unroll
        for (int n = 0; n < 4; ++n) {
            bh[n] = *(const f16x8*)&sm[cur][2][kb][wc * 64 + n * 16 + r16][0];
            bl[n] = *(const f16x8*)&sm[cur][3][kb][wc * 64 + n * 16 + r16][0];
        }
        // term-major: 16 independent MFMAs between accumulator reuses;
        // per-acc order stays hh -> hl -> lh (bit-identical to serial form)
#pragma unroll
        for (int m = 0; m < 4; ++m)
#pragma unroll
            for (int n = 0; n < 4; ++n)
                acc[m][n] = __builtin_amdgcn_mfma_f32_16x16x32_f16(ah[m], bh[n], acc[m][n], 0, 0, 0);
#pragma unroll
        for (int m = 0; m < 4; ++m)
#pragma unroll
            for (int n = 0; n < 4; ++n)
                acc[m][n] = __builtin_amdgcn_mfma_f32_16x16x32_f16(ah[m], bl[n], acc[m][n], 0, 0, 0);
#pragma unroll
        for (int m = 0; m < 4; ++m)
#pragma unroll
            for (int n = 0; n < 4; ++n)
                acc[m][n] = __builtin_amdgcn_mfma_f32_16x16x32_f16(al[m], bh[n], acc[m][n], 0, 0, 0);

        __syncthreads();   // drains vmcnt (stage t+1 complete) + lgkm; one barrier per K-step
        cur ^= 1;
    }
    // epilogue: C/D frag: col = lane&15, row = (lane>>4)*4 + j
#pragma unroll
    for (int m = 0; m < 4; ++m)
#pragma unroll
        for (int n = 0; n < 4; ++n) {
            int cc = col0 + wc * 64 + n * 16 + r16;
            float b = (cc < 512) ? bias_l[cc] : bias_r[cc - 512];
#pragma unroll
            for (int j = 0; j < 4; ++j) {
                int rr = row0 + wr * 64 + m * 16 + kb * 4 + j;
                C[(size_t)rr * Nn + cc] = acc[m][n][j] * WINV + b;
            }
        }
}

// ---------------- CSR build ----------------
__global__ void count_edges(const int* __restrict__ dst, int E_in, int* __restrict__ cnt)
{
    int e = blockIdx.x * blockDim.x + threadIdx.x;
    if (e < E_in) atomicAdd(&cnt[dst[e]], 1);
}

__global__ void fill_edges(const int* __restrict__ src, const int* __restrict__ dst,
                           int E_in, int* __restrict__ next, int* __restrict__ csr)
{
    int e = blockIdx.x * blockDim.x + threadIdx.x;
    if (e < E_in) {
        int p = atomicAdd(&next[dst[e]], 1);
        csr[p] = src[e];
    }
}

__global__ __launch_bounds__(1024) void scan_excl(const int* __restrict__ cnt, int n,
                                                  int* __restrict__ off, int* __restrict__ next)
{
    __shared__ int bsum[1024];
    int t = threadIdx.x;
    int chunk = (n + 1023) >> 10;
    int lo = t * chunk, hi = min(n, lo + chunk);
    int s = 0;
    for (int i = lo; i < hi; ++i) s += cnt[i];
    bsum[t] = s;
    __syncthreads();
    for (int d = 1; d < 1024; d <<= 1) {
        int v = (t >= d) ? bsum[t - d] : 0;
        __syncthreads();
        bsum[t] += v;
        __syncthreads();
    }
    int run = t ? bsum[t - 1] : 0;
    for (int i = lo; i < hi; ++i) { off[i] = run; next[i] = run; run += cnt[i]; }
    if (t == 1023) off[n] = bsum[1023];
}

__global__ void remap_edges(const int* __restrict__ src, const int* __restrict__ dst,
                            int E_in, const int* __restrict__ nmap,
                            int* __restrict__ es2, int* __restrict__ ed2,
                            int* __restrict__ ec2, int* __restrict__ cnt2)
{
    int e = blockIdx.x * blockDim.x + threadIdx.x;
    if (e >= E_in) return;
    int ns = nmap[src[e]], nd = nmap[dst[e]];
    if (ns >= 0 && nd >= 0) {
        int pos = atomicAdd(ec2, 1);
        es2[pos] = ns; ed2[pos] = nd;
        atomicAdd(&cnt2[nd], 1);
    }
}

__global__ void fill_edges_dyn(const int* __restrict__ es, const int* __restrict__ ed,
                               const int* __restrict__ ec, int* __restrict__ next,
                               int* __restrict__ csr)
{
    int e = blockIdx.x * blockDim.x + threadIdx.x;
    if (e < *ec) {
        int p = atomicAdd(&next[ed[e]], 1);
        csr[p] = es[e];
    }
}

// ---------------- GATv2 aggregation: one wave per dst node ----------------
__global__ __launch_bounds__(256) void gatv2_agg(
    const float* __restrict__ XL, const float* __restrict__ XR, int ldx,
    const int* __restrict__ csr_src, const int* __restrict__ off,
    const float* __restrict__ att, const float* __restrict__ bias,
    float* __restrict__ out, int n)
{
    int nwg = gridDim.x;
    int q = nwg >> 3;
    int swz = (blockIdx.x & 7) * q + (blockIdx.x >> 3);
    int wid = swz * 4 + (threadIdx.x >> 6);
    int lane = threadIdx.x & 63;
    if (wid >= n) return;
    const int f0 = lane * 8;
    float xr[8], atv[8], acc[8];
    {
        float4 r0 = *(const float4*)&XR[(size_t)wid * ldx + f0];
        float4 r1 = *(const float4*)&XR[(size_t)wid * ldx + f0 + 4];
        xr[0]=r0.x; xr[1]=r0.y; xr[2]=r0.z; xr[3]=r0.w;
        xr[4]=r1.x; xr[5]=r1.y; xr[6]=r1.z; xr[7]=r1.w;
        float4 t0 = *(const float4*)&att[f0];
        float4 t1 = *(const float4*)&att[f0 + 4];
        atv[0]=t0.x; atv[1]=t0.y; atv[2]=t0.z; atv[3]=t0.w;
        atv[4]=t1.x; atv[5]=t1.y; atv[6]=t1.z; atv[7]=t1.w;
#pragma unroll
        for (int j = 0; j < 8; ++j) acc[j] = 0.f;
    }
    float m = -INFINITY, ssum = 0.f;
    int e0 = off[wid], e1 = off[wid + 1];
    for (int e = e0 - 1; e < e1; ++e) {
        int s = (e < e0) ? wid : csr_src[e];
        float xl[8], part = 0.f;
        float4 l0 = *(const float4*)&XL[(size_t)s * ldx + f0];
        float4 l1 = *(const float4*)&XL[(size_t)s * ldx + f0 + 4];
        xl[0]=l0.x; xl[1]=l0.y; xl[2]=l0.z; xl[3]=l0.w;
        xl[4]=l1.x; xl[5]=l1.y; xl[6]=l1.z; xl[7]=l1.w;
#pragma unroll
        for (int j = 0; j < 8; ++j) {
            float v = xl[j] + xr[j];
            v = (v > 0.f) ? v : SLOPE * v;
            part += v * atv[j];
        }
        part += __shfl_xor(part, 1);
        part += __shfl_xor(part, 2);
        part += __shfl_xor(part, 4);
        part += __shfl_xor(part, 8);
        float mn = fmaxf(m, part);
        float scale = __expf(m - mn);
        float p = __expf(part - mn);
        ssum = ssum * scale + p;
#pragma unroll
        for (int j = 0; j < 8; ++j) acc[j] = acc[j] * scale + p * xl[j];
        m = mn;
    }
    float inv = 1.f / ssum;
#pragma unroll
    for (int j = 0; j < 8; ++j) {
        float v = acc[j] * inv;
        v += __shfl_xor(v, 16);
        v += __shfl_xor(v, 32);
        if (lane < 16) {
            int c = lane * 8 + j;
            float r = 0.25f * v + bias[c];
            out[(size_t)wid * 128 + c] = fmaxf(r, 0.f);
        }
    }
}

// ---------------- SAGE pooling score ----------------
__global__ __launch_bounds__(256) void sage_score(
    const float* __restrict__ X, const int* __restrict__ csr_src,
    const int* __restrict__ off, const float* __restrict__ Wn,
    const float* __restrict__ Wr, const float* __restrict__ bs,
    float* __restrict__ score, int n)
{
    int wid = (blockIdx.x * blockDim.x + threadIdx.x) >> 6;
    int lane = threadIdx.x & 63;
    if (wid >= n) return;
    int c0 = lane * 2;
    int e0 = off[wid], e1 = off[wid + 1];
    float a0 = 0.f, a1 = 0.f;
    for (int e = e0; e < e1; ++e) {
        int s = csr_src[e];
        float2 v = *(const float2*)&X[(size_t)s * 128 + c0];
        a0 += v.x; a1 += v.y;
    }
    float inv = 1.f / fmaxf((float)(e1 - e0), 1.f);
    float2 xv = *(const float2*)&X[(size_t)wid * 128 + c0];
    float part = a0 * inv * Wn[c0] + a1 * inv * Wn[c0 + 1] + xv.x * Wr[c0] + xv.y * Wr[c0 + 1];
#pragma unroll
    for (int sh = 1; sh < 64; sh <<= 1) part += __shfl_xor(part, sh);
    if (lane == 0) score[wid] = part + bs[0];
}

// ---------------- SAGPooling top-k (exact jax.lax.top_k rank) ----------------
__global__ __launch_bounds__(512) void pool_rank(const float* __restrict__ score,
                                                 int npg, int k, int* __restrict__ nmap)
{
    __shared__ float s[512];
    int b = blockIdx.x, t = threadIdx.x;
    const float* sc = score + (size_t)b * npg;
    if (t < npg) s[t] = sc[t];
    __syncthreads();
    if (t < npg) {
        float mine = s[t];
        int rank = 0;
        for (int j = 0; j < npg; ++j) {
            float v = s[j];
            rank += (v > mine) || (v == mine && j < t);
        }
        nmap[(size_t)b * npg + t] = (rank < k) ? (b * k + rank) : -1;
    }
}

// gather + tanh gate; optionally emit fp16 split for the next GEMM
__global__ void pool_gather(const float* __restrict__ X, const float* __restrict__ score,
                            const int* __restrict__ nmap, float* __restrict__ Xn,
                            f16* __restrict__ Xh, f16* __restrict__ Xl)
{
    int i = blockIdx.x, c = threadIdx.x;  // 128 threads
    int nid = nmap[i];
    if (nid < 0) return;
    float t = tanhf(score[i]);
    float v = X[(size_t)i * 128 + c] * t;
    Xn[(size_t)nid * 128 + c] = v;
    if (Xh) {
        f16 h = (f16)v;
        Xh[(size_t)nid * 128 + c] = h;
        Xl[(size_t)nid * 128 + c] = (f16)(v - (float)h);
    }
}

// ---------------- global max pool (parallel, encoded atomicMax) ----------------
__global__ void gmp2(const float* __restrict__ X, int npg, int rpb,
                     unsigned* __restrict__ outEnc)
{
    int b = blockIdx.x, q = blockIdx.y, c = threadIdx.x;  // 128 threads
    int r0 = q * rpb, r1 = min(npg, r0 + rpb);
    if (r0 >= r1) return;
    const float* p = X + ((size_t)b * npg + r0) * 128 + c;
    float m = -INFINITY;
    for (int i = r0; i < r1; ++i, p += 128) m = fmaxf(m, *p);
    atomicMax(&outEnc[b * 128 + c], enc_f(m));
}

// ---------------- final: relu((x1+x2+x3) @ Wf + bf), decoding gmp results ----------------
__global__ void final_mlp(const unsigned* __restrict__ xg,
                          const float* __restrict__ Wf,
                          const float* __restrict__ bf, float* __restrict__ out)
{
    int b = blockIdx.x, o = threadIdx.x;  // 64 threads
    float acc = bf[o];
    for (int c = 0; c < 128; ++c) {
        int i = b * 128 + c;
        float xv = dec_f(xg[i]) + dec_f(xg[4096 + i]) + dec_f(xg[8192 + i]);
        acc += xv * Wf[c * 64 + o];
    }
    out[b * 64 + o] = fmaxf(acc, 0.f);
}

// ---------------- host orchestration ----------------
static inline size_t alignup(size_t x) { return (x + 255) & ~(size_t)255; }

extern "C" void kernel_launch(void* const* d_in, const int* in_sizes, int n_in,
                              void* d_out, int out_size, void* d_ws, size_t ws_size,
                              hipStream_t stream)
{
    const float* x_feat = (const float*)d_in[0];
    const int*   ei     = (const int*)d_in[1];
    const float* Wl1  = (const float*)d_in[3];
    const float* bl1  = (const float*)d_in[4];
    const float* Wr1  = (const float*)d_in[5];
    const float* br1  = (const float*)d_in[6];
    const float* att1 = (const float*)d_in[7];
    const float* bias1= (const float*)d_in[8];
    const float* Wl2  = (const float*)d_in[9];
    const float* bl2  = (const float*)d_in[10];
    const float* Wr2  = (const float*)d_in[11];
    const float* br2  = (const float*)d_in[12];
    const float* att2 = (const float*)d_in[13];
    const float* bias2= (const float*)d_in[14];
    const float* Wsn  = (const float*)d_in[15];
    const float* Wsr  = (const float*)d_in[16];
    const float* bs   = (const float*)d_in[17];
    const float* Wf   = (const float*)d_in[18];
    const float* bf   = (const float*)d_in[19];
    float* out = (float*)d_out;

    const int* e_src = ei;
    const int* e_dst = ei + ETOT;

    // ---- workspace carve-up ----
    char* ws = (char*)d_ws;
    size_t o = 0;
    auto take = [&](size_t bytes) { size_t r = o; o = alignup(o + bytes); return r; };
    float* C1   = (float*)(ws + take((size_t)NTOT * 1024 * 4));  // XL|XR fp32 (both layers)
    float* H1   = (float*)(ws + take((size_t)NTOT * 128 * 4));
    float* PX   = (float*)(ws + take((size_t)N2 * 128 * 4));
    float* H2   = (float*)(ws + take((size_t)N2 * 128 * 4));
    float* P2X  = (float*)(ws + take((size_t)N3 * 128 * 4));
    f16*   Ah1  = (f16*)(ws + take((size_t)NTOT * 512 * 2));
    f16*   Al1  = (f16*)(ws + take((size_t)NTOT * 512 * 2));
    f16*   Wh1  = (f16*)(ws + take((size_t)1024 * 512 * 2));
    f16*   Wo1  = (f16*)(ws + take((size_t)1024 * 512 * 2));
    f16*   Wh2  = (f16*)(ws + take((size_t)1024 * 128 * 2));
    f16*   Wo2  = (f16*)(ws + take((size_t)1024 * 128 * 2));
    f16*   PXh  = (f16*)(ws + take((size_t)N2 * 128 * 2));
    f16*   PXl  = (f16*)(ws + take((size_t)N2 * 128 * 2));
    float* score= (float*)(ws + take((size_t)NTOT * 4));
    int*   nmap = (int*)(ws + take((size_t)NTOT * 4));
    int*   cnt  = (int*)(ws + take((size_t)(NTOT + 1) * 4));
    int*   offs = (int*)(ws + take((size_t)(NTOT + 1) * 4));
    int*   nxt  = (int*)(ws + take((size_t)(NTOT + 1) * 4));
    int*   csr1 = (int*)(ws + take((size_t)ETOT * 4));
    int*   es2  = (int*)(ws + take((size_t)ETOT * 4));
    int*   ed2  = (int*)(ws + take((size_t)ETOT * 4));
    int*   csr2 = (int*)(ws + take((size_t)ETOT * 4));
    int*   ec2  = (int*)(ws + take(256));
    unsigned* xg = (unsigned*)(ws + take((size_t)3 * NB * 128 * 4));  // x1|x2|x3 encoded
    (void)ws_size; (void)in_sizes; (void)n_in; (void)out_size;

    // ---- prep: split x_feat, transpose+split weights, zero readouts ----
    hipMemsetAsync(xg, 0, (size_t)3 * NB * 128 * 4, stream);
    split_a<<<(NTOT * 512 / 8) / 256, 256, 0, stream>>>(x_feat, Ah1, Al1, NTOT * 512 / 8);
    prep_w<<<dim3(512 / 32, 32), 256, 0, stream>>>(Wl1, Wr1, Wh1, Wo1, 512);
    prep_w<<<dim3(128 / 32, 32), 256, 0, stream>>>(Wl2, Wr2, Wh2, Wo2, 128);

    // ---- layer 1 transform: C1 = x @ [Wl1|Wr1] + [bl1|br1]  (split-fp16 MFMA) ----
    gemm_split<<<dim3(8, NTOT / 128), 256, 0, stream>>>(Ah1, Al1, Wh1, Wo1, bl1, br1, C1, NTOT, 512);

    // ---- CSR (by dst) ----
    hipMemsetAsync(cnt, 0, (size_t)(NTOT + 1) * 4, stream);
    count_edges<<<ETOT / 256, 256, 0, stream>>>(e_dst, ETOT, cnt);
    scan_excl<<<1, 1024, 0, stream>>>(cnt, NTOT, offs, nxt);
    fill_edges<<<ETOT / 256, 256, 0, stream>>>(e_src, e_dst, ETOT, nxt, csr1);

    // ---- GATv2 layer 1 + relu -> H1; x1 = gmp(H1) ----
    gatv2_agg<<<NTOT / 4, 256, 0, stream>>>(C1, C1 + 512, 1024, csr1, offs, att1, bias1, H1, NTOT);
    gmp2<<<dim3(NB, 8), 128, 0, stream>>>(H1, NPG, 64, xg);

    // ---- SAGE score 1 + pool 1 (emits fp16 split of PX); x2 = gmp(PX) ----
    sage_score<<<NTOT / 4, 256, 0, stream>>>(H1, csr1, offs, Wsn, Wsr, bs, score, NTOT);
    pool_rank<<<NB, 512, 0, stream>>>(score, NPG, K1, nmap);
    pool_gather<<<NTOT, 128, 0, stream>>>(H1, score, nmap, PX, PXh, PXl);
    gmp2<<<dim3(NB, 4), 128, 0, stream>>>(PX, K1, 77, xg + 4096);

    // ---- remap + compact edges, CSR2 ----
    hipMemsetAsync(cnt, 0, (size_t)(NTOT + 1) * 4, stream);
    hipMemsetAsync(ec2, 0, 4, stream);
    remap_edges<<<ETOT / 256, 256, 0, stream>>>(e_src, e_dst, ETOT, nmap, es2, ed2, ec2, cnt);
    scan_excl<<<1, 1024, 0, stream>>>(cnt, N2, offs, nxt);
    fill_edges_dyn<<<ETOT / 256, 256, 0, stream>>>(es2, ed2, ec2, nxt, csr2);

    // ---- layer 2 transform: C1 = PX @ [Wl2|Wr2] + [bl2|br2]  (K=128) ----
    gemm_split<<<dim3(8, N2 / 128), 256, 0, stream>>>(PXh, PXl, Wh2, Wo2, bl2, br2, C1, N2, 128);

    // ---- GATv2 layer 2 + relu -> H2 ----
    gatv2_agg<<<(N2 + 3) / 4, 256, 0, stream>>>(C1, C1 + 512, 1024, csr2, offs, att2, bias2, H2, N2);

    // ---- SAGE score 2 + pool 2; x3 = gmp(P2X) ----
    sage_score<<<(N2 + 3) / 4, 256, 0, stream>>>(H2, csr2, offs, Wsn, Wsr, bs, score, N2);
    pool_rank<<<NB, 512, 0, stream>>>(score, K1, K2, nmap);
    pool_gather<<<N2, 128, 0, stream>>>(H2, score, nmap, P2X, (f16*)nullptr, (f16*)nullptr);
    gmp2<<<dim3(NB, 4), 128, 0, stream>>>(P2X, K2, 47, xg + 8192);

    // ---- final MLP ----
    final_mlp<<<NB, 64, 0, stream>>>(xg, Wf, bf, out);
}